// Round 10
// baseline (380.509 us; speedup 1.0000x reference)
//
#include <hip/hip_runtime.h>

#define NN 50000     // nodes
#define NE 800000    // edges
#define DD 64        // channels
#define NG 512       // graphs

// ---------------- CSR build v3: fixed-capacity bucket sort ----------------
// R11: CAP=1280 (+8 sigma) removes count+scan kernels; col keeps gaps.
// R12: layer fusion REVERTED (occupancy 28% starved the gather).
// R13-R15: channel-quartering + XCD-pinning REVERTED — FETCH floor
// ~105 MB/layer is compulsory 8-XCD broadcast; v5 gather structure best.
// R16-R18: bf16 gather (row 128 B) halved agg FETCH (~55 MB/layer) — WIN;
// bf16 conversion must stay OUT of dense (R17: epilogue edit collapsed
// VGPR 105->68, LDS re-reads, 2x slower; R18 standalone to_bf16_k fixed).
// R19 (this round): agg time barely moved (37 vs 40 us) despite halved
// bytes -> REQUEST-rate-bound: v8 = 16 req/edge-row (16 x 8B). v9 gather
// reshapes to 8 edge-groups x 8 channel-octs, uint4 (16B) loads ->
// 8 req/edge-row. Predicted agg ~20-24 us/layer.

#define BSH 6
#define NBU ((NN + 63) >> BSH)          // 782
#define CAP 1280                        // bucket capacity (mean 1023, sigma 32)
#define EPB 8192                        // edges per block in scatter
#define NBLK ((NE + EPB - 1) / EPB)     // 98

__global__ void bucket_scatter_k(const int* __restrict__ src, const int* __restrict__ dst,
                                 int* __restrict__ bcur, int* __restrict__ ebuf) {
    __shared__ int hist[NBU];
    __shared__ int base[NBU];
    for (int i = threadIdx.x; i < NBU; i += 256) hist[i] = 0;
    __syncthreads();
    int e0 = blockIdx.x * EPB;
    int e1 = min(e0 + EPB, NE);
    for (int e = e0 + threadIdx.x; e < e1; e += 256)
        atomicAdd(&hist[dst[e] >> BSH], 1);
    __syncthreads();
    for (int i = threadIdx.x; i < NBU; i += 256) {
        int c = hist[i];
        base[i] = c ? (i * CAP + atomicAdd(&bcur[i], c)) : 0;
        hist[i] = 0;
    }
    __syncthreads();
    for (int e = e0 + threadIdx.x; e < e1; e += 256) {
        int s = src[e];
        int d = dst[e];
        int b = d >> BSH;
        int r = atomicAdd(&hist[b], 1);
        ebuf[base[b] + r] = (s << 6) | (d & 63);
    }
}

__global__ void bucket_finalize_k(const int* __restrict__ ebuf, const int* __restrict__ bcur,
                                  int* __restrict__ deg, int* __restrict__ start,
                                  int* __restrict__ col) {
    __shared__ int dcnt[64];
    __shared__ int dstart[64];
    const int b = blockIdx.x;
    const int t = threadIdx.x;
    const int e0 = b * CAP;
    const int n = bcur[b];
    if (t < 64) dcnt[t] = 0;
    __syncthreads();
    for (int i = t; i < n; i += 256)
        atomicAdd(&dcnt[ebuf[e0 + i] & 63], 1);
    __syncthreads();
    if (t < 64) {   // wave 0: 64-entry exclusive scan
        int v = dcnt[t];
        int incl = v;
#pragma unroll
        for (int off = 1; off < 64; off <<= 1) {
            int u = __shfl_up(incl, off, 64);
            if (t >= off) incl += u;
        }
        dstart[t] = e0 + incl - v;
        int node = (b << BSH) + t;
        if (node < NN) { deg[node] = v; start[node] = e0 + incl - v; }
        dcnt[t] = 0;
    }
    __syncthreads();
    for (int i = t; i < n; i += 256) {
        int v = ebuf[e0 + i];
        int ln = v & 63;
        int r = atomicAdd(&dcnt[ln], 1);
        col[dstart[ln] + r] = v >> 6;
    }
}

// ---------------- bf16 helpers ----------------

__device__ __forceinline__ unsigned bf16rne(float f) {
    unsigned u = __float_as_uint(f);
    return (u + 0x7FFFu + ((u >> 16) & 1u)) >> 16;
}

// accumulate 2 packed bf16 (uint) into two floats of a float4 half
__device__ __forceinline__ void accb2(float& a, float& b, unsigned v) {
    a += __uint_as_float(v << 16);
    b += __uint_as_float(v & 0xFFFF0000u);
}

// accumulate 8 packed bf16 (uint4) into two float4 accumulators
__device__ __forceinline__ void accb8(float4& a0, float4& a1, uint4 v) {
    accb2(a0.x, a0.y, v.x);
    accb2(a0.z, a0.w, v.y);
    accb2(a1.x, a1.y, v.z);
    accb2(a1.z, a1.w, v.w);
}

__global__ void to_bf16_k(const float* __restrict__ in, ushort* __restrict__ outb) {
    int i = blockIdx.x * blockDim.x + threadIdx.x;   // one float4 -> uint2
    if (i < NN * DD / 4) {
        float4 v = ((const float4*)in)[i];
        uint2 w;
        w.x = bf16rne(v.x) | (bf16rne(v.y) << 16);
        w.y = bf16rne(v.z) | (bf16rne(v.w) << 16);
        ((uint2*)outb)[i] = w;
    }
}

// ---------------- aggregation v9: bf16 gather, 16B requests ----------------
// one wave per node; lanes = 8 edge-groups (eg = lane>>3) x 8 channel-octs
// (oc = lane&7; 8 bf16 = 16 B = one uint4). Per 32-edge chunk: one col
// load, nb via __shfl, 4 independent uint4 loads (edges eg+8k, k=0..3;
// k=2,3 under wave-uniform cnt>16). 8 requests/edge-row (v8 was 16 x 8B)
// — attacks the L2 request-issue bound identified in R19.
__global__ void aggregate_b_k(const ushort* __restrict__ hb, const int* __restrict__ start,
                              const int* __restrict__ deg, const int* __restrict__ col,
                              float* __restrict__ agg) {
    int w = (blockIdx.x * blockDim.x + threadIdx.x) >> 6;
    int lane = threadIdx.x & 63;
    if (w >= NN) return;
    int eg = lane >> 3;   // edge group 0..7
    int oc = lane & 7;    // channel oct: ch 8oc..8oc+7
    int s = start[w], d = deg[w];
    float4 acc0 = make_float4(0.f, 0.f, 0.f, 0.f);   // ch 8oc+0..3
    float4 acc1 = make_float4(0.f, 0.f, 0.f, 0.f);   // ch 8oc+4..7
    const uint4* h4b = (const uint4*)hb;   // row stride = 8 uint4 = 128 B
    for (int base = 0; base < d; base += 32) {
        int idx = base + (lane & 31);
        int cv = col[s + ((idx < d) ? idx : 0)];   // one load, 32 distinct addrs
        int cnt = d - base;                        // >0; wave-uniform
        uint4 v0, v1;
        {
            int n0 = __shfl(cv, eg + 0, 64);
            int n1 = __shfl(cv, eg + 8, 64);
            v0 = h4b[(size_t)n0 * 8 + oc];
            v1 = h4b[(size_t)n1 * 8 + oc];
        }
        uint4 v2, v3;
        bool hi = (cnt > 16);                      // wave-uniform branch
        if (hi) {
            int n2 = __shfl(cv, eg + 16, 64);
            int n3 = __shfl(cv, eg + 24, 64);
            v2 = h4b[(size_t)n2 * 8 + oc];
            v3 = h4b[(size_t)n3 * 8 + oc];
        }
        if (eg + 0 < cnt) accb8(acc0, acc1, v0);
        if (eg + 8 < cnt) accb8(acc0, acc1, v1);
        if (hi) {
            if (eg + 16 < cnt) accb8(acc0, acc1, v2);
            if (eg + 24 < cnt) accb8(acc0, acc1, v3);
        }
    }
    // reduce over 8 edge groups (eg = lane bits 3..5): xor 8,16,32
#pragma unroll
    for (int off = 8; off <= 32; off <<= 1) {
        acc0.x += __shfl_xor(acc0.x, off, 64);
        acc0.y += __shfl_xor(acc0.y, off, 64);
        acc0.z += __shfl_xor(acc0.z, off, 64);
        acc0.w += __shfl_xor(acc0.w, off, 64);
        acc1.x += __shfl_xor(acc1.x, off, 64);
        acc1.y += __shfl_xor(acc1.y, off, 64);
        acc1.z += __shfl_xor(acc1.z, off, 64);
        acc1.w += __shfl_xor(acc1.w, off, 64);
    }
    if (eg == 0) {   // lanes 0..7: oc-th 32B of the row
        float4* row = (float4*)(agg + (size_t)w * DD);
        row[2 * oc + 0] = acc0;
        row[2 * oc + 1] = acc1;
    }
}

// ---------------- dense layer v4 (proven R5/R7; byte-exact R3 revert) ----------------
// out = relu([hin] + agg @ Wrel^T + b + hin @ Wroot^T)
// block = 256 = 4 waves, 64 nodes/block. lane = node, wave = 16-output slice.
// Two channel-half passes keep register demand ~105 VGPR (no spill at 3
// blocks/CU). Weights wave-uniform -> scalar s_load; activations in registers.
// R18: do NOT add epilogue code here — R17's bf16 mirror write collapsed
// VGPR 105->68 (compiler re-read LDS per oo-iter, 2x slowdown).
template <int RESID>
__global__ void __launch_bounds__(256, 3)
dense_layer_k(const float* __restrict__ agg, const float* __restrict__ hin,
              const float* __restrict__ wrel, const float* __restrict__ brel,
              const float* __restrict__ wroot, float* __restrict__ hout) {
    __shared__ float A[64][68];   // stride 68 dwords: b128 transpose reads at 8-phase floor
    __shared__ float H[64][68];

    const int t = threadIdx.x;
    const int tile = blockIdx.x * 64;
    const int nrows = min(64, NN - tile);

    const float4* agg4 = (const float4*)(agg + (size_t)tile * DD);
    const float4* hin4 = (const float4*)(hin + (size_t)tile * DD);
#pragma unroll
    for (int k = 0; k < 4; ++k) {
        int idx = t + k * 256;
        int row = idx >> 4, cq = idx & 15;
        if (row < nrows) {
            *(float4*)&A[row][4 * cq] = agg4[idx];
            *(float4*)&H[row][4 * cq] = hin4[idx];
        }
    }
    __syncthreads();

    const int lane = t & 63;
    const int wv = __builtin_amdgcn_readfirstlane(t >> 6);
    const int o0 = wv * 16;

    float4 a4[8], h4[8];
    float acc[16];

#pragma unroll
    for (int cq = 0; cq < 8; ++cq) {
        a4[cq] = *(const float4*)&A[lane][4 * cq];
        h4[cq] = *(const float4*)&H[lane][4 * cq];
    }
#pragma unroll
    for (int oo = 0; oo < 16; ++oo) {
        int o = o0 + oo;
        const float* w1 = wrel + o * DD;
        const float* w2 = wroot + o * DD;
        float s0 = 0.f, s1 = 0.f, s2 = 0.f, s3 = 0.f;
#pragma unroll
        for (int cq = 0; cq < 8; ++cq) {
            s0 += a4[cq].x * w1[4 * cq + 0] + h4[cq].x * w2[4 * cq + 0];
            s1 += a4[cq].y * w1[4 * cq + 1] + h4[cq].y * w2[4 * cq + 1];
            s2 += a4[cq].z * w1[4 * cq + 2] + h4[cq].z * w2[4 * cq + 2];
            s3 += a4[cq].w * w1[4 * cq + 3] + h4[cq].w * w2[4 * cq + 3];
        }
        acc[oo] = (s0 + s1) + (s2 + s3);
    }

#pragma unroll
    for (int cq = 0; cq < 8; ++cq) {
        a4[cq] = *(const float4*)&A[lane][32 + 4 * cq];
        h4[cq] = *(const float4*)&H[lane][32 + 4 * cq];
    }
    __syncthreads();
    float* Out = &A[0][0];
#pragma unroll
    for (int oo = 0; oo < 16; ++oo) {
        int o = o0 + oo;
        const float* w1 = wrel + o * DD + 32;
        const float* w2 = wroot + o * DD + 32;
        float s0 = acc[oo], s1 = 0.f, s2 = 0.f, s3 = 0.f;
#pragma unroll
        for (int cq = 0; cq < 8; ++cq) {
            s0 += a4[cq].x * w1[4 * cq + 0] + h4[cq].x * w2[4 * cq + 0];
            s1 += a4[cq].y * w1[4 * cq + 1] + h4[cq].y * w2[4 * cq + 1];
            s2 += a4[cq].z * w1[4 * cq + 2] + h4[cq].z * w2[4 * cq + 2];
            s3 += a4[cq].w * w1[4 * cq + 3] + h4[cq].w * w2[4 * cq + 3];
        }
        Out[lane * 68 + o] = (s0 + s1) + (s2 + s3) + brel[o];
    }
    __syncthreads();

    float4* out4 = (float4*)(hout + (size_t)tile * DD);
#pragma unroll
    for (int k = 0; k < 4; ++k) {
        int idx = t + k * 256;
        int row = idx >> 4, cq = idx & 15;
        if (row < nrows) {
            float4 r = *(const float4*)&A[row][4 * cq];
            if (RESID) {
                float4 hr = *(const float4*)&H[row][4 * cq];
                r.x += hr.x; r.y += hr.y; r.z += hr.z; r.w += hr.w;
            }
            r.x = fmaxf(r.x, 0.f); r.y = fmaxf(r.y, 0.f);
            r.z = fmaxf(r.z, 0.f); r.w = fmaxf(r.w, 0.f);
            out4[idx] = r;
        }
    }
}

// ---------------- pooling (batch is sorted) ----------------

__global__ void pool_k(const float* __restrict__ h, const int* __restrict__ batch,
                       float* __restrict__ sums, int* __restrict__ cnt) {
    const int NP = 32;
    int w = (blockIdx.x * blockDim.x + threadIdx.x) >> 6;
    int lane = threadIdx.x & 63;
    int n0 = w * NP;
    if (n0 >= NN) return;
    int n1 = min(n0 + NP, NN);
    int g = batch[n0];
    float acc = 0.f;
    int run = 0;
    for (int i = n0; i < n1; ++i) {
        int gi = batch[i];
        if (gi != g) {
            atomicAdd(&sums[g * DD + lane], acc);
            if (lane == 0) atomicAdd(&cnt[g], run);
            acc = 0.f; run = 0; g = gi;
        }
        acc += h[i * DD + lane];
        run++;
    }
    atomicAdd(&sums[g * DD + lane], acc);
    if (lane == 0) atomicAdd(&cnt[g], run);
}

// ---------------- head: mean -> linear -> softmax ----------------

__global__ void head_k(const float* __restrict__ sums, const int* __restrict__ cnt,
                       const float* __restrict__ lin_w, const float* __restrict__ lin_b,
                       float* __restrict__ out) {
    int g = blockIdx.x * (blockDim.x >> 6) + (threadIdx.x >> 6);
    int o = threadIdx.x & 63;
    if (g >= NG) return;
    float c = (float)cnt[g];
    float inv = 1.0f / fmaxf(c, 1.0f);
    float acc = lin_b[o];
#pragma unroll 8
    for (int k = 0; k < DD; ++k) {
        acc += sums[g * DD + k] * inv * lin_w[o * DD + k];
    }
    float m = acc;
#pragma unroll
    for (int off = 32; off; off >>= 1) m = fmaxf(m, __shfl_xor(m, off, 64));
    float e = __expf(acc - m);
    float s = e;
#pragma unroll
    for (int off = 32; off; off >>= 1) s += __shfl_xor(s, off, 64);
    out[g * DD + o] = e / s;
}

// ---------------- driver ----------------

extern "C" void kernel_launch(void* const* d_in, const int* in_sizes, int n_in,
                              void* d_out, int out_size, void* d_ws, size_t ws_size,
                              hipStream_t stream) {
    const float* x      = (const float*)d_in[0];
    const int*   edge   = (const int*)d_in[1];   // [2, E]: src = edge, dst = edge+NE
    const int*   batch  = (const int*)d_in[2];
    const float* rel_w  = (const float*)d_in[3]; // [L, D, D]
    const float* rel_b  = (const float*)d_in[4]; // [L, D]
    const float* root_w = (const float*)d_in[5]; // [L, D, D]
    const float* lin_w  = (const float*)d_in[6]; // [D, D]
    const float* lin_b  = (const float*)d_in[7]; // [D]
    float* out = (float*)d_out;

    const int* src = edge;
    const int* dst = edge + NE;

    // workspace carve (all 256B aligned)
    char* p = (char*)d_ws;
    auto carve = [&](size_t bytes) {
        char* r = p;
        p += (bytes + 255) & ~(size_t)255;
        return (void*)r;
    };
    float*  hA   = (float*)carve((size_t)NN * DD * 4);
    float*  hB   = (float*)carve((size_t)NN * DD * 4);
    float*  agg  = (float*)carve((size_t)NN * DD * 4);
    ushort* xb   = (ushort*)carve((size_t)NN * DD * 2);  // bf16 ping
    ushort* hb   = (ushort*)carve((size_t)NN * DD * 2);  // bf16 pong
    int*    col  = (int*)carve((size_t)NBU * CAP * 4);   // 4.0 MB, bucket gaps unread
    int*    ebuf = (int*)carve((size_t)NBU * CAP * 4);   // 4.0 MB packed (src<<6)|dlow
    int*    strt = (int*)carve((size_t)NN * 4);
    int*    deg  = (int*)carve((size_t)NN * 4);
    // ---- contiguous zero region (single memset) ----
    char* zbase = p;
    float* sums = (float*)carve((size_t)NG * DD * 4);
    int*   cnt  = (int*)carve((size_t)NG * 4);
    int*   bcur = (int*)carve((size_t)NBU * 4);
    size_t zbytes = (size_t)(p - zbase);

    (void)hipMemsetAsync(zbase, 0, zbytes, stream);

    const int cvtBlocks = (NN * DD / 4 + 255) / 256;

    // x -> bf16 once; CSR build v3 (2 kernels)
    to_bf16_k<<<cvtBlocks, 256, 0, stream>>>(x, xb);
    bucket_scatter_k<<<NBLK, 256, 0, stream>>>(src, dst, bcur, ebuf);
    bucket_finalize_k<<<NBU, 256, 0, stream>>>(ebuf, bcur, deg, strt, col);

    const int aggBlocks = (NN + 3) / 4;     // 4 waves (nodes) per block
    const int dnsBlocks = (NN + 63) / 64;   // 64 nodes per block

    // layer 0: gather xb -> agg; dense(x) -> hA; hA -> hb (bf16)
    aggregate_b_k<<<aggBlocks, 256, 0, stream>>>(xb, strt, deg, col, agg);
    dense_layer_k<0><<<dnsBlocks, 256, 0, stream>>>(agg, x, rel_w, rel_b, root_w, hA);
    to_bf16_k<<<cvtBlocks, 256, 0, stream>>>(hA, hb);
    // layer 1: gather hb; dense(hA) -> hB; hB -> xb
    aggregate_b_k<<<aggBlocks, 256, 0, stream>>>(hb, strt, deg, col, agg);
    dense_layer_k<0><<<dnsBlocks, 256, 0, stream>>>(agg, hA, rel_w + 4096, rel_b + 64,
                                                    root_w + 4096, hB);
    to_bf16_k<<<cvtBlocks, 256, 0, stream>>>(hB, xb);
    // layer 2: gather xb; dense(hB) -> hA; hA -> hb
    aggregate_b_k<<<aggBlocks, 256, 0, stream>>>(xb, strt, deg, col, agg);
    dense_layer_k<0><<<dnsBlocks, 256, 0, stream>>>(agg, hB, rel_w + 2 * 4096, rel_b + 2 * 64,
                                                    root_w + 2 * 4096, hA);
    to_bf16_k<<<cvtBlocks, 256, 0, stream>>>(hA, hb);
    // layer 3 (residual): gather hb; dense(hA) -> hB; hB -> xb
    aggregate_b_k<<<aggBlocks, 256, 0, stream>>>(hb, strt, deg, col, agg);
    dense_layer_k<1><<<dnsBlocks, 256, 0, stream>>>(agg, hA, rel_w + 3 * 4096, rel_b + 3 * 64,
                                                    root_w + 3 * 4096, hB);
    to_bf16_k<<<cvtBlocks, 256, 0, stream>>>(hB, xb);
    // layer 4 (residual): gather xb; dense(hB) -> hA (pool reads fp32 hA)
    aggregate_b_k<<<aggBlocks, 256, 0, stream>>>(xb, strt, deg, col, agg);
    dense_layer_k<1><<<dnsBlocks, 256, 0, stream>>>(agg, hB, rel_w + 4 * 4096, rel_b + 4 * 64,
                                                    root_w + 4 * 4096, hA);

    // pool + head
    const int wavesPool = (NN + 31) / 32;
    pool_k<<<(wavesPool + 3) / 4, 256, 0, stream>>>(hA, batch, sums, cnt);
    head_k<<<(NG + 3) / 4, 256, 0, stream>>>(sums, cnt, lin_w, lin_b, out);
}

// Round 11
// 291.153 us; speedup vs baseline: 1.3069x; 1.3069x over previous
//
#include <hip/hip_runtime.h>

#define NN 50000     // nodes
#define NE 800000    // edges
#define DD 64        // channels
#define NG 512       // graphs

// ---------------- session ledger ----------------
// R11: CSR v3 fixed-capacity bucket sort (CAP=1280, +8 sigma) — kept.
// R12: layer fusion REVERTED (occupancy collapse starved gather).
// R13-R15: quartering/XCD-pin REVERTED (broadcast floor, overheads).
// R16-R18: bf16 gather WIN; bf16 convert must stay OUT of VALU-dense
//   (R17: epilogue edit collapsed VGPR 105->68, 2x slower).
// R19/R20: halving gather requests (16B loads) NEUTRAL -> gather is
//   L3-random-service-bound (~1.6 TB/s), ~35 us/layer is its floor.
// R21 (this round): dense VALU (27 us/layer, 20% of FMA peak) -> MFMA
//   bf16 GEMM: [50K x 128] @ wcat^T, K=128 concat [agg|h], 16x16x32
//   frags, LDS-staged epilogue (bias+resid+relu), writes bf16 directly
//   (kills per-layer to_bf16) + fp32 only on last layer for pool.

#define BSH 6
#define NBU ((NN + 63) >> BSH)          // 782
#define CAP 1280                        // bucket capacity (mean 1023, sigma 32)
#define EPB 8192                        // edges per block in scatter
#define NBLK ((NE + EPB - 1) / EPB)     // 98

typedef __attribute__((ext_vector_type(8))) short bf16x8;
typedef __attribute__((ext_vector_type(4))) float f32x4;

__global__ void bucket_scatter_k(const int* __restrict__ src, const int* __restrict__ dst,
                                 int* __restrict__ bcur, int* __restrict__ ebuf) {
    __shared__ int hist[NBU];
    __shared__ int base[NBU];
    for (int i = threadIdx.x; i < NBU; i += 256) hist[i] = 0;
    __syncthreads();
    int e0 = blockIdx.x * EPB;
    int e1 = min(e0 + EPB, NE);
    for (int e = e0 + threadIdx.x; e < e1; e += 256)
        atomicAdd(&hist[dst[e] >> BSH], 1);
    __syncthreads();
    for (int i = threadIdx.x; i < NBU; i += 256) {
        int c = hist[i];
        base[i] = c ? (i * CAP + atomicAdd(&bcur[i], c)) : 0;
        hist[i] = 0;
    }
    __syncthreads();
    for (int e = e0 + threadIdx.x; e < e1; e += 256) {
        int s = src[e];
        int d = dst[e];
        int b = d >> BSH;
        int r = atomicAdd(&hist[b], 1);
        ebuf[base[b] + r] = (s << 6) | (d & 63);
    }
}

__global__ void bucket_finalize_k(const int* __restrict__ ebuf, const int* __restrict__ bcur,
                                  int* __restrict__ deg, int* __restrict__ start,
                                  int* __restrict__ col) {
    __shared__ int dcnt[64];
    __shared__ int dstart[64];
    const int b = blockIdx.x;
    const int t = threadIdx.x;
    const int e0 = b * CAP;
    const int n = bcur[b];
    if (t < 64) dcnt[t] = 0;
    __syncthreads();
    for (int i = t; i < n; i += 256)
        atomicAdd(&dcnt[ebuf[e0 + i] & 63], 1);
    __syncthreads();
    if (t < 64) {   // wave 0: 64-entry exclusive scan
        int v = dcnt[t];
        int incl = v;
#pragma unroll
        for (int off = 1; off < 64; off <<= 1) {
            int u = __shfl_up(incl, off, 64);
            if (t >= off) incl += u;
        }
        dstart[t] = e0 + incl - v;
        int node = (b << BSH) + t;
        if (node < NN) { deg[node] = v; start[node] = e0 + incl - v; }
        dcnt[t] = 0;
    }
    __syncthreads();
    for (int i = t; i < n; i += 256) {
        int v = ebuf[e0 + i];
        int ln = v & 63;
        int r = atomicAdd(&dcnt[ln], 1);
        col[dstart[ln] + r] = v >> 6;
    }
}

// ---------------- bf16 helpers ----------------

__device__ __forceinline__ unsigned bf16rne(float f) {
    unsigned u = __float_as_uint(f);
    return (u + 0x7FFFu + ((u >> 16) & 1u)) >> 16;
}

// accumulate 8 packed bf16 (uint4) into two float4 accumulators
__device__ __forceinline__ void accb2(float& a, float& b, unsigned v) {
    a += __uint_as_float(v << 16);
    b += __uint_as_float(v & 0xFFFF0000u);
}
__device__ __forceinline__ void accb8(float4& a0, float4& a1, uint4 v) {
    accb2(a0.x, a0.y, v.x);
    accb2(a0.z, a0.w, v.y);
    accb2(a1.x, a1.y, v.z);
    accb2(a1.z, a1.w, v.w);
}

// expand 4 packed bf16 (uint2) -> float4
__device__ __forceinline__ float4 expb(uint2 v) {
    float4 r;
    r.x = __uint_as_float(v.x << 16);
    r.y = __uint_as_float(v.x & 0xFFFF0000u);
    r.z = __uint_as_float(v.y << 16);
    r.w = __uint_as_float(v.y & 0xFFFF0000u);
    return r;
}

__global__ void to_bf16_k(const float* __restrict__ in, ushort* __restrict__ outb) {
    int i = blockIdx.x * blockDim.x + threadIdx.x;   // one float4 -> uint2
    if (i < NN * DD / 4) {
        float4 v = ((const float4*)in)[i];
        uint2 w;
        w.x = bf16rne(v.x) | (bf16rne(v.y) << 16);
        w.y = bf16rne(v.z) | (bf16rne(v.w) << 16);
        ((uint2*)outb)[i] = w;
    }
}

// weights -> bf16 concat wcat[l][o][k]: k<64 from rel_w, k>=64 from root_w
__global__ void cvt_w_k(const float* __restrict__ rel_w, const float* __restrict__ root_w,
                        ushort* __restrict__ wcat) {
    int i = blockIdx.x * blockDim.x + threadIdx.x;
    if (i < 5 * 64 * 128) {
        int k = i & 127;
        int o = (i >> 7) & 63;
        int l = i >> 13;
        float v = (k < 64) ? rel_w[l * 4096 + o * 64 + k]
                           : root_w[l * 4096 + o * 64 + (k - 64)];
        wcat[i] = (ushort)bf16rne(v);
    }
}

// ---------------- aggregation v9b: bf16 gather, 16B requests, bf16 out ----------------
// one wave per node; lanes = 8 edge-groups x 8 channel-octs (16 B uint4).
// L3-random-service-bound (~35 us/layer, R19/R20) — structure frozen.
// R21: output is bf16 (dense is now MFMA and consumes bf16 directly).
__global__ void aggregate_b_k(const ushort* __restrict__ hb, const int* __restrict__ start,
                              const int* __restrict__ deg, const int* __restrict__ col,
                              ushort* __restrict__ aggb) {
    int w = (blockIdx.x * blockDim.x + threadIdx.x) >> 6;
    int lane = threadIdx.x & 63;
    if (w >= NN) return;
    int eg = lane >> 3;   // edge group 0..7
    int oc = lane & 7;    // channel oct: ch 8oc..8oc+7
    int s = start[w], d = deg[w];
    float4 acc0 = make_float4(0.f, 0.f, 0.f, 0.f);   // ch 8oc+0..3
    float4 acc1 = make_float4(0.f, 0.f, 0.f, 0.f);   // ch 8oc+4..7
    const uint4* h4b = (const uint4*)hb;   // row stride = 8 uint4 = 128 B
    for (int base = 0; base < d; base += 32) {
        int idx = base + (lane & 31);
        int cv = col[s + ((idx < d) ? idx : 0)];   // one load, 32 distinct addrs
        int cnt = d - base;                        // >0; wave-uniform
        uint4 v0, v1;
        {
            int n0 = __shfl(cv, eg + 0, 64);
            int n1 = __shfl(cv, eg + 8, 64);
            v0 = h4b[(size_t)n0 * 8 + oc];
            v1 = h4b[(size_t)n1 * 8 + oc];
        }
        uint4 v2, v3;
        bool hi = (cnt > 16);                      // wave-uniform branch
        if (hi) {
            int n2 = __shfl(cv, eg + 16, 64);
            int n3 = __shfl(cv, eg + 24, 64);
            v2 = h4b[(size_t)n2 * 8 + oc];
            v3 = h4b[(size_t)n3 * 8 + oc];
        }
        if (eg + 0 < cnt) accb8(acc0, acc1, v0);
        if (eg + 8 < cnt) accb8(acc0, acc1, v1);
        if (hi) {
            if (eg + 16 < cnt) accb8(acc0, acc1, v2);
            if (eg + 24 < cnt) accb8(acc0, acc1, v3);
        }
    }
    // reduce over 8 edge groups (eg = lane bits 3..5): xor 8,16,32
#pragma unroll
    for (int off = 8; off <= 32; off <<= 1) {
        acc0.x += __shfl_xor(acc0.x, off, 64);
        acc0.y += __shfl_xor(acc0.y, off, 64);
        acc0.z += __shfl_xor(acc0.z, off, 64);
        acc0.w += __shfl_xor(acc0.w, off, 64);
        acc1.x += __shfl_xor(acc1.x, off, 64);
        acc1.y += __shfl_xor(acc1.y, off, 64);
        acc1.z += __shfl_xor(acc1.z, off, 64);
        acc1.w += __shfl_xor(acc1.w, off, 64);
    }
    if (eg == 0) {   // lanes 0..7: oc-th 16 B (8 bf16) of the row
        uint4 wv;
        wv.x = bf16rne(acc0.x) | (bf16rne(acc0.y) << 16);
        wv.y = bf16rne(acc0.z) | (bf16rne(acc0.w) << 16);
        wv.z = bf16rne(acc1.x) | (bf16rne(acc1.y) << 16);
        wv.w = bf16rne(acc1.z) | (bf16rne(acc1.w) << 16);
        ((uint4*)(aggb + (size_t)w * DD))[oc] = wv;
    }
}

// ---------------- dense layer v6: MFMA bf16 GEMM ----------------
// C[64 nodes][64 out] = X[64][128] @ wcat_l^T, X = [aggb | hbin] bf16.
// block = 256 = 4 waves; wave wr owns 16-node slab, loops 4 out-tiles x
// 4 K-steps of mfma_f32_16x16x32_bf16. Frags (16x16x32): A lane holds
// A[lane&15][8*(lane>>4)+j]; B lane holds B[8*(lane>>4)+j][lane&15] =
// Wrow[lane&15][k..]; C/D col=lane&15, row=4*(lane>>4)+reg (m89).
// Epilogue via LDS [64][68]: bias + (RESID: + bf16 hbin) + relu ->
// bf16 out (uint2); fp32 out only when LAST (pool input).
// Buffers padded +64 rows: last block (16 valid rows) frag-loads OOB rows
// harmlessly (C rows never written past nrows).
template <int RESID, int LAST>
__global__ void __launch_bounds__(256, 4)
dense_mfma_k(const ushort* __restrict__ aggb, const ushort* __restrict__ hbin,
             const ushort* __restrict__ wcat, const float* __restrict__ brel,
             ushort* __restrict__ hbout, float* __restrict__ houtf) {
    __shared__ float Cs[64][68];
    const int t = threadIdx.x;
    const int lane = t & 63;
    const int wr = t >> 6;            // wave id = node-slab 0..3
    const int tile = blockIdx.x * 64;
    const int nrows = min(64, NN - tile);

    const int r16 = lane & 15;        // A row in slab / B out-col in tile
    const int kg = lane >> 4;         // k-group 0..3 (8 contiguous k)

    const size_t node = (size_t)(tile + wr * 16 + r16);   // may pad-read past NN
    bf16x8 a0 = *(const bf16x8*)(aggb + node * DD +  0 + kg * 8);
    bf16x8 a1 = *(const bf16x8*)(aggb + node * DD + 32 + kg * 8);
    bf16x8 a2 = *(const bf16x8*)(hbin + node * DD +  0 + kg * 8);
    bf16x8 a3 = *(const bf16x8*)(hbin + node * DD + 32 + kg * 8);

#pragma unroll
    for (int oc = 0; oc < 4; ++oc) {
        const ushort* wrow = wcat + (size_t)(oc * 16 + r16) * 128 + kg * 8;
        bf16x8 b0 = *(const bf16x8*)(wrow + 0);
        bf16x8 b1 = *(const bf16x8*)(wrow + 32);
        bf16x8 b2 = *(const bf16x8*)(wrow + 64);
        bf16x8 b3 = *(const bf16x8*)(wrow + 96);
        f32x4 c = {0.f, 0.f, 0.f, 0.f};
        c = __builtin_amdgcn_mfma_f32_16x16x32_bf16(a0, b0, c, 0, 0, 0);
        c = __builtin_amdgcn_mfma_f32_16x16x32_bf16(a1, b1, c, 0, 0, 0);
        c = __builtin_amdgcn_mfma_f32_16x16x32_bf16(a2, b2, c, 0, 0, 0);
        c = __builtin_amdgcn_mfma_f32_16x16x32_bf16(a3, b3, c, 0, 0, 0);
        float bias = brel[oc * 16 + r16];
#pragma unroll
        for (int r = 0; r < 4; ++r)
            Cs[wr * 16 + kg * 4 + r][oc * 16 + r16] = c[r] + bias;
    }
    __syncthreads();

    const uint2* hbin2 = (const uint2*)hbin + (size_t)tile * 16;   // row = 16 uint2
    uint2* outb2 = (uint2*)hbout + (size_t)tile * 16;
    float4* out4 = (float4*)(houtf + (size_t)tile * DD);
#pragma unroll
    for (int k = 0; k < 4; ++k) {
        int idx = t + k * 256;
        int row = idx >> 4, cq = idx & 15;
        if (row < nrows) {
            float4 r = *(const float4*)&Cs[row][4 * cq];
            if (RESID) {
                float4 hv = expb(hbin2[idx]);
                r.x += hv.x; r.y += hv.y; r.z += hv.z; r.w += hv.w;
            }
            r.x = fmaxf(r.x, 0.f); r.y = fmaxf(r.y, 0.f);
            r.z = fmaxf(r.z, 0.f); r.w = fmaxf(r.w, 0.f);
            uint2 wb;
            wb.x = bf16rne(r.x) | (bf16rne(r.y) << 16);
            wb.y = bf16rne(r.z) | (bf16rne(r.w) << 16);
            outb2[idx] = wb;
            if (LAST) out4[idx] = r;
        }
    }
}

// ---------------- pooling (batch is sorted) ----------------

__global__ void pool_k(const float* __restrict__ h, const int* __restrict__ batch,
                       float* __restrict__ sums, int* __restrict__ cnt) {
    const int NP = 32;
    int w = (blockIdx.x * blockDim.x + threadIdx.x) >> 6;
    int lane = threadIdx.x & 63;
    int n0 = w * NP;
    if (n0 >= NN) return;
    int n1 = min(n0 + NP, NN);
    int g = batch[n0];
    float acc = 0.f;
    int run = 0;
    for (int i = n0; i < n1; ++i) {
        int gi = batch[i];
        if (gi != g) {
            atomicAdd(&sums[g * DD + lane], acc);
            if (lane == 0) atomicAdd(&cnt[g], run);
            acc = 0.f; run = 0; g = gi;
        }
        acc += h[i * DD + lane];
        run++;
    }
    atomicAdd(&sums[g * DD + lane], acc);
    if (lane == 0) atomicAdd(&cnt[g], run);
}

// ---------------- head: mean -> linear -> softmax ----------------

__global__ void head_k(const float* __restrict__ sums, const int* __restrict__ cnt,
                       const float* __restrict__ lin_w, const float* __restrict__ lin_b,
                       float* __restrict__ out) {
    int g = blockIdx.x * (blockDim.x >> 6) + (threadIdx.x >> 6);
    int o = threadIdx.x & 63;
    if (g >= NG) return;
    float c = (float)cnt[g];
    float inv = 1.0f / fmaxf(c, 1.0f);
    float acc = lin_b[o];
#pragma unroll 8
    for (int k = 0; k < DD; ++k) {
        acc += sums[g * DD + k] * inv * lin_w[o * DD + k];
    }
    float m = acc;
#pragma unroll
    for (int off = 32; off; off >>= 1) m = fmaxf(m, __shfl_xor(m, off, 64));
    float e = __expf(acc - m);
    float s = e;
#pragma unroll
    for (int off = 32; off; off >>= 1) s += __shfl_xor(s, off, 64);
    out[g * DD + o] = e / s;
}

// ---------------- driver ----------------

extern "C" void kernel_launch(void* const* d_in, const int* in_sizes, int n_in,
                              void* d_out, int out_size, void* d_ws, size_t ws_size,
                              hipStream_t stream) {
    const float* x      = (const float*)d_in[0];
    const int*   edge   = (const int*)d_in[1];   // [2, E]: src = edge, dst = edge+NE
    const int*   batch  = (const int*)d_in[2];
    const float* rel_w  = (const float*)d_in[3]; // [L, D, D]
    const float* rel_b  = (const float*)d_in[4]; // [L, D]
    const float* root_w = (const float*)d_in[5]; // [L, D, D]
    const float* lin_w  = (const float*)d_in[6]; // [D, D]
    const float* lin_b  = (const float*)d_in[7]; // [D]
    float* out = (float*)d_out;

    const int* src = edge;
    const int* dst = edge + NE;

    // workspace carve (all 256B aligned)
    char* p = (char*)d_ws;
    auto carve = [&](size_t bytes) {
        char* r = p;
        p += (bytes + 255) & ~(size_t)255;
        return (void*)r;
    };
    const size_t PADROWS = 64;   // frag-load overrun guard for last block
    float*  hAf  = (float*)carve((size_t)NN * DD * 4);                    // fp32 final (pool)
    ushort* xb   = (ushort*)carve((size_t)(NN + PADROWS) * DD * 2);       // bf16 ping
    ushort* hb   = (ushort*)carve((size_t)(NN + PADROWS) * DD * 2);       // bf16 pong
    ushort* aggb = (ushort*)carve((size_t)(NN + PADROWS) * DD * 2);       // bf16 aggregate
    ushort* wcat = (ushort*)carve((size_t)5 * 64 * 128 * 2);              // bf16 weights
    int*    col  = (int*)carve((size_t)NBU * CAP * 4);   // 4.0 MB, bucket gaps unread
    int*    ebuf = (int*)carve((size_t)NBU * CAP * 4);   // 4.0 MB packed (src<<6)|dlow
    int*    strt = (int*)carve((size_t)NN * 4);
    int*    deg  = (int*)carve((size_t)NN * 4);
    // ---- contiguous zero region (single memset) ----
    char* zbase = p;
    float* sums = (float*)carve((size_t)NG * DD * 4);
    int*   cnt  = (int*)carve((size_t)NG * 4);
    int*   bcur = (int*)carve((size_t)NBU * 4);
    size_t zbytes = (size_t)(p - zbase);

    (void)hipMemsetAsync(zbase, 0, zbytes, stream);

    const int cvtBlocks = (NN * DD / 4 + 255) / 256;

    // conversions + CSR build v3
    to_bf16_k<<<cvtBlocks, 256, 0, stream>>>(x, xb);
    cvt_w_k<<<(5 * 64 * 128 + 255) / 256, 256, 0, stream>>>(rel_w, root_w, wcat);
    bucket_scatter_k<<<NBLK, 256, 0, stream>>>(src, dst, bcur, ebuf);
    bucket_finalize_k<<<NBU, 256, 0, stream>>>(ebuf, bcur, deg, strt, col);

    const int aggBlocks = (NN + 3) / 4;     // 4 waves (nodes) per block
    const int dnsBlocks = (NN + 63) / 64;   // 64 nodes per block

    // layer 0: gather xb -> aggb; mfma-dense -> hb
    aggregate_b_k<<<aggBlocks, 256, 0, stream>>>(xb, strt, deg, col, aggb);
    dense_mfma_k<0, 0><<<dnsBlocks, 256, 0, stream>>>(aggb, xb, wcat, rel_b, hb, hAf);
    // layer 1: gather hb -> aggb; dense -> xb
    aggregate_b_k<<<aggBlocks, 256, 0, stream>>>(hb, strt, deg, col, aggb);
    dense_mfma_k<0, 0><<<dnsBlocks, 256, 0, stream>>>(aggb, hb, wcat + 8192, rel_b + 64,
                                                      xb, hAf);
    // layer 2: gather xb; dense -> hb
    aggregate_b_k<<<aggBlocks, 256, 0, stream>>>(xb, strt, deg, col, aggb);
    dense_mfma_k<0, 0><<<dnsBlocks, 256, 0, stream>>>(aggb, xb, wcat + 2 * 8192,
                                                      rel_b + 2 * 64, hb, hAf);
    // layer 3 (residual): gather hb; dense -> xb
    aggregate_b_k<<<aggBlocks, 256, 0, stream>>>(hb, strt, deg, col, aggb);
    dense_mfma_k<1, 0><<<dnsBlocks, 256, 0, stream>>>(aggb, hb, wcat + 3 * 8192,
                                                      rel_b + 3 * 64, xb, hAf);
    // layer 4 (residual, LAST): gather xb; dense -> hb + fp32 hAf for pool
    aggregate_b_k<<<aggBlocks, 256, 0, stream>>>(xb, strt, deg, col, aggb);
    dense_mfma_k<1, 1><<<dnsBlocks, 256, 0, stream>>>(aggb, xb, wcat + 4 * 8192,
                                                      rel_b + 4 * 64, hb, hAf);

    // pool + head
    const int wavesPool = (NN + 31) / 32;
    pool_k<<<(wavesPool + 3) / 4, 256, 0, stream>>>(hAf, batch, sums, cnt);
    head_k<<<(NG + 3) / 4, 256, 0, stream>>>(sums, cnt, lin_w, lin_b, out);
}